// Round 9
// baseline (810.132 us; speedup 1.0000x reference)
//
#include <hip/hip_runtime.h>
#include <hip/hip_bf16.h>
#include <stdint.h>

typedef __bf16 bf16x8 __attribute__((ext_vector_type(8)));
typedef float f32x4 __attribute__((ext_vector_type(4)));
typedef float f32x16 __attribute__((ext_vector_type(16)));
typedef unsigned short us8 __attribute__((ext_vector_type(8)));

__device__ __forceinline__ float bf2f(unsigned short u) {
    return __uint_as_float(((unsigned)u) << 16);
}
__device__ __forceinline__ unsigned short f2bf(float f) {
    __bf16 b = (__bf16)f;  // RNE
    return __builtin_bit_cast(unsigned short, b);
}

__device__ __forceinline__ void gload16(const char* g, char* l) {
    __builtin_amdgcn_global_load_lds(
        (const __attribute__((address_space(1))) void*)g,
        (__attribute__((address_space(3))) void*)l, 16, 0, 0);
}

// ---------------------------------------------------------------------------
// Transpose + cast: in (K x N) f32  ->  out (N x K) bf16
// ---------------------------------------------------------------------------
__global__ __launch_bounds__(256) void transpose_cast(
    const float* __restrict__ in, unsigned short* __restrict__ out,
    int K, int N)
{
    __shared__ float tile[32][33];
    const int tx = threadIdx.x, ty = threadIdx.y;  // (32, 8)
    const int n0 = blockIdx.x * 32, k0 = blockIdx.y * 32;
    #pragma unroll
    for (int i = 0; i < 32; i += 8)
        tile[ty + i][tx] = in[(long)(k0 + ty + i) * N + n0 + tx];
    __syncthreads();
    #pragma unroll
    for (int i = 0; i < 32; i += 8)
        out[(long)(n0 + ty + i) * K + k0 + tx] = f2bf(tile[tx][ty + i]);
}

// ---------------------------------------------------------------------------
// Elementwise cast f32 -> bf16 (vectorized, grid-stride)
// ---------------------------------------------------------------------------
__global__ __launch_bounds__(256) void cast_f32_bf16(
    const float* __restrict__ in, unsigned short* __restrict__ out, long n)
{
    const long stride = (long)gridDim.x * 256 * 8;
    for (long i = ((long)blockIdx.x * 256 + threadIdx.x) * 8; i < n; i += stride) {
        const f32x4 u0 = *(const f32x4*)&in[i];
        const f32x4 u1 = *(const f32x4*)&in[i + 4];
        us8 w;
        #pragma unroll
        for (int e = 0; e < 4; ++e) { w[e] = f2bf(u0[e]); w[e + 4] = f2bf(u1[e]); }
        *(us8*)&out[i] = w;
    }
}

// ---------------------------------------------------------------------------
// GEMM: C(M,N) = A(M,K) @ BT(N,K)^T + bias(N)       (A, BT bf16; K == 1024)
// 256x256 tile, BK=64, 512 threads (8 waves, 2M x 4N), 128KB dbuf LDS.
// r8's 8-phase counted-lgkm read-ahead schedule, converted to
// v_mfma_f32_32x32x16_bf16 (2382 TF ceiling vs 2075 for 16x16): 4 MFMA per
// phase, same per-phase read counts (4 A / 2 B b128), same staging points
// (S3/S5 A, S6/S7 B), same counted waits (lgkm 4/2, vmcnt(4) at S5).
// A frag: lane l holds A[row=l&31][k=(l>>5)*8..+8].  C/D: col=lane&31,
// row=(reg&3)+8*(reg>>2)+4*(lane>>5)  [m74/m101-verified].
// ---------------------------------------------------------------------------
#define MFMA32(a, b, c) __builtin_amdgcn_mfma_f32_32x32x16_bf16(a, b, c, 0, 0, 0)
#define BAR __builtin_amdgcn_s_barrier()
#define SB  __builtin_amdgcn_sched_barrier(0)
#define P1_ __builtin_amdgcn_s_setprio(1);
#define P0_ __builtin_amdgcn_s_setprio(0);

// 4 MFMA: M-blocks {RO, RO+1} x N-block CO x kslices {0,1} of the half.
#define MFMA_H32(AA, BB, RO, CO)                                               \
    acc[(RO)][(CO)]   = MFMA32(AA[0], BB[0], acc[(RO)][(CO)]);                 \
    acc[(RO)][(CO)]   = MFMA32(AA[1], BB[1], acc[(RO)][(CO)]);                 \
    acc[(RO)+1][(CO)] = MFMA32(AA[2], BB[0], acc[(RO)+1][(CO)]);               \
    acc[(RO)+1][(CO)] = MFMA32(AA[3], BB[1], acc[(RO)+1][(CO)]);

// A: 2 M-blocks (32 rows each) x 2 kslices -> 4 b128.  HIOFF: 0 or 8192.
#define RD_A4(DST, BUFOFF, HIOFF, KA, KB2)                                     \
    DST[0] = *(const bf16x8*)(smem + (BUFOFF) + aBase + (HIOFF) + 0*4096 + (KA));  \
    DST[1] = *(const bf16x8*)(smem + (BUFOFF) + aBase + (HIOFF) + 0*4096 + (KB2)); \
    DST[2] = *(const bf16x8*)(smem + (BUFOFF) + aBase + (HIOFF) + 1*4096 + (KA));  \
    DST[3] = *(const bf16x8*)(smem + (BUFOFF) + aBase + (HIOFF) + 1*4096 + (KB2));

// B: 1 N-block (32 cols) x 2 kslices -> 2 b128.  NOFF: 0 or 4096.
#define RD_B2(DST, BUFOFF, NOFF, KA, KB2)                                      \
    DST[0] = *(const bf16x8*)(smem + (BUFOFF) + bBase + (NOFF) + (KA));        \
    DST[1] = *(const bf16x8*)(smem + (BUFOFF) + bBase + (NOFF) + (KB2));

// One K-tile = 8 phases S0..S7.  SG/SR are LITERAL 0/1 (folded).
#define TILE8(T_, BUF, OBUF, SG, SR)                                           \
  do {                                                                         \
    const long gk = (long)((T_) + 2) * 128;                                    \
    /* S0: rd AH0; mfma AL0xBL0 */                                             \
    RD_A4(AH0, BUF, 8192, kk0, kk1)                                            \
    SB; asm volatile("s_waitcnt lgkmcnt(4)"); SB;                              \
    P1_ MFMA_H32(AL0, BL0, 0, 0) P0_                                           \
    /* S1: rd BH0; mfma AH0xBL0 */                                             \
    RD_B2(BH0, BUF, 4096, kk0, kk1)                                            \
    SB; asm volatile("s_waitcnt lgkmcnt(2)"); SB;                              \
    P1_ MFMA_H32(AH0, BL0, 2, 0) P0_                                           \
    /* S2: rd AL1; mfma AH0xBH0 */                                             \
    RD_A4(AL1, BUF, 0, kk2, kk3)                                               \
    SB; asm volatile("s_waitcnt lgkmcnt(4)"); SB;                              \
    P1_ MFMA_H32(AH0, BH0, 2, 1) P0_                                           \
    /* S3: rd BL1; stage A j0,j2; mfma AL0xBH0 */                              \
    BAR; RD_B2(BL1, BUF, 0, kk2, kk3)                                          \
    if (SG) {                                                                  \
        gload16(aStage + (long)(0*64)*Kb + gk, smem + (BUF) + 0*8192 + ldsW);  \
        gload16(aStage + (long)(2*64)*Kb + gk, smem + (BUF) + 2*8192 + ldsW);  \
    }                                                                          \
    SB; asm volatile("s_waitcnt lgkmcnt(2)"); SB;                              \
    P1_ MFMA_H32(AL0, BH0, 0, 1) P0_                                           \
    /* S4: rd AH1; mfma AL1xBL1 */                                             \
    RD_A4(AH1, BUF, 8192, kk2, kk3)                                            \
    SB; asm volatile("s_waitcnt lgkmcnt(4)"); SB;                              \
    P1_ MFMA_H32(AL1, BL1, 0, 0) P0_                                           \
    /* S5: rd BH1; stage A j1,j3; mfma AH1xBL1; counted vmcnt */               \
    BAR; RD_B2(BH1, BUF, 4096, kk2, kk3)                                       \
    if (SG) {                                                                  \
        gload16(aStage + (long)(1*64)*Kb + gk, smem + (BUF) + 1*8192 + ldsW);  \
        gload16(aStage + (long)(3*64)*Kb + gk, smem + (BUF) + 3*8192 + ldsW);  \
    }                                                                          \
    SB; asm volatile("s_waitcnt lgkmcnt(2)"); SB;                              \
    P1_ MFMA_H32(AH1, BL1, 2, 0) P0_                                           \
    SB;                                                                        \
    if (SG) asm volatile("s_waitcnt vmcnt(4)");                                \
    else    asm volatile("s_waitcnt vmcnt(0)");                                \
    SB;                                                                        \
    /* S6: rd BL0'(OBUF); stage B j0,j1; mfma AH1xBH1 */                       \
    BAR;                                                                       \
    if (SR) { RD_B2(BL0, OBUF, 0, kk0, kk1) }                                  \
    if (SG) {                                                                  \
        gload16(bStage + (long)(0*64)*Kb + gk, smem + (BUF) + 32768 + 0*8192 + ldsW); \
        gload16(bStage + (long)(1*64)*Kb + gk, smem + (BUF) + 32768 + 1*8192 + ldsW); \
    }                                                                          \
    SB;                                                                        \
    if (SR) asm volatile("s_waitcnt lgkmcnt(2)");                              \
    else    asm volatile("s_waitcnt lgkmcnt(0)");                              \
    SB;                                                                        \
    P1_ MFMA_H32(AH1, BH1, 2, 1) P0_                                           \
    /* S7: rd AL0'(OBUF); stage B j2,j3; mfma AL1xBH1 */                       \
    BAR;                                                                       \
    if (SR) { RD_A4(AL0, OBUF, 0, kk0, kk1) }                                  \
    if (SG) {                                                                  \
        gload16(bStage + (long)(2*64)*Kb + gk, smem + (BUF) + 32768 + 2*8192 + ldsW); \
        gload16(bStage + (long)(3*64)*Kb + gk, smem + (BUF) + 32768 + 3*8192 + ldsW); \
    }                                                                          \
    SB;                                                                        \
    if (SR) asm volatile("s_waitcnt lgkmcnt(4)");                              \
    else    asm volatile("s_waitcnt lgkmcnt(0)");                              \
    SB;                                                                        \
    P1_ MFMA_H32(AL1, BH1, 0, 1) P0_                                           \
  } while (0)

template<bool OUT_BF16>
__global__ __launch_bounds__(512, 2)
void gemm256(const unsigned short* __restrict__ A,   // M x K bf16
             const unsigned short* __restrict__ BT,  // N x K bf16
             const float* __restrict__ bias,
             void* __restrict__ Cp,
             int M, int N, int K)
{
    extern __shared__ char smem[];   // 131072: 2 bufs x (A 32K | B 32K)
    const int tid  = threadIdx.x;
    const int lane = tid & 63;
    const int w    = tid >> 6;      // wave 0..7
    const int wm   = w >> 2;        // 0..1 (M split)
    const int wn   = w & 3;         // 0..3 (N split)

    // XCD-bijective swizzle (launcher guarantees gridDim.x % 8 == 0)
    const int nwg  = gridDim.x;
    const int bid0 = blockIdx.x;
    const int bid  = (bid0 & 7) * (nwg >> 3) + (bid0 >> 3);
    const int nbx  = N >> 8;
    const int bx   = bid % nbx, by = bid / nbx;
    const long rowStart = (long)by * 256;
    const int  colStart = bx * 256;

    const long Kb = (long)K * 2;     // row stride bytes (K == 1024, KT == 16)

    // staging: instr (mat, j) covers tile rows j*64 + w*8 + (lane>>3)
    const int srow = w * 8 + (lane >> 3);
    const int scol = ((lane & 7) ^ (lane >> 3)) << 4;   // inverse-swizzled src col
    const char* aStage = (const char*)A  + (rowStart + srow) * Kb + scol;
    const char* bStage = (const char*)BT + ((long)colStart + srow) * Kb + scol;
    const int ldsW = w * 1024;

    // fragment-read offsets (swizzled), 32x32x16 layout
    const int fr32 = lane & 31;                    // row/col within block
    const int kq2  = lane >> 5;                    // 0..1 (k-group)
    const int swz  = (fr32 & 7) << 4;
    const int kk0 = (0   + kq2 * 16) ^ swz;        // kslice byte offsets
    const int kk1 = (32  + kq2 * 16) ^ swz;
    const int kk2 = (64  + kq2 * 16) ^ swz;
    const int kk3 = (96  + kq2 * 16) ^ swz;
    const int aBase = (wm * 128 + fr32) * 128;         // bytes, A region
    const int bBase = 32768 + (wn * 64 + fr32) * 128;  // bytes, B region

    f32x16 acc[4][2] = {};   // [M-block 0..3][N-block 0..1], 128 regs
    bf16x8 AL0[4], AH0[4], AL1[4], AH1[4], BL0[2], BH0[2], BL1[2], BH1[2];

    // ---- prologue: stage K-tiles 0 (buf0) and 1 (buf1) ----
    #pragma unroll
    for (int tt = 0; tt < 2; ++tt) {
        #pragma unroll
        for (int j = 0; j < 4; ++j)
            gload16(aStage + (long)(j * 64) * Kb + (long)tt * 128,
                    smem + tt * 65536 + j * 8192 + ldsW);
        #pragma unroll
        for (int j = 0; j < 4; ++j)
            gload16(bStage + (long)(j * 64) * Kb + (long)tt * 128,
                    smem + tt * 65536 + 32768 + j * 8192 + ldsW);
    }
    asm volatile("s_waitcnt vmcnt(8)");   // tile 0 landed; tile 1 in flight
    BAR;                                   // publish tile-0 stages
    RD_B2(BL0, 0, 0, kk0, kk1)             // preload S0 operands (6 reads)
    RD_A4(AL0, 0, 0, kk0, kk1)
    // S0's lgkmcnt(4) (after its 4 AH0 reads) drains these 6.

    #pragma unroll 1
    for (int tp = 0; tp < 7; ++tp) {       // tiles 0..13, full pipeline
        TILE8(2 * tp,     0,     65536, 1, 1);
        TILE8(2 * tp + 1, 65536, 0,     1, 1);
    }
    TILE8(14, 0,     65536, 0, 1);         // no staging; drain vmcnt
    TILE8(15, 65536, 0,     0, 0);         // tail: no next-tile reads

    // ---- epilogue: 32x32 C/D: col=lane&31, row=(reg&3)+8*(reg>>2)+4*kq2 ----
    float bv[2];
    #pragma unroll
    for (int nb = 0; nb < 2; ++nb)
        bv[nb] = bias[colStart + wn * 64 + nb * 32 + fr32];
    #pragma unroll
    for (int mi = 0; mi < 4; ++mi) {
        #pragma unroll
        for (int nb = 0; nb < 2; ++nb) {
            const int col = colStart + wn * 64 + nb * 32 + fr32;
            #pragma unroll
            for (int reg = 0; reg < 16; ++reg) {
                const long row = rowStart + wm * 128 + mi * 32
                               + (reg & 3) + 8 * (reg >> 2) + 4 * kq2;
                const float val = acc[mi][nb][reg] + bv[nb];
                if constexpr (OUT_BF16)
                    ((unsigned short*)Cp)[row * N + col] = f2bf(val);
                else
                    ((float*)Cp)[row * N + col] = val;
            }
        }
    }
}

// ---------------------------------------------------------------------------
// Per-token head-mixing attention (unchanged, verified).
// ---------------------------------------------------------------------------
__global__ __launch_bounds__(256) void attn_kernel(
    const unsigned short* __restrict__ qkv, unsigned short* __restrict__ out)
{
    __shared__ unsigned short qkvs[4][3072];
    __shared__ float ps[4][256];
    __shared__ unsigned short os[4][1024];
    const int tid = threadIdx.x, lane = tid & 63, wave = tid >> 6;
    const long blockTok = (long)blockIdx.x * 4;

    const unsigned short* src = qkv + blockTok * 3072;
    unsigned short* dstBase = &qkvs[0][0];
    #pragma unroll
    for (int i = 0; i < 6; ++i) {
        const int o = (i * 256 + tid) * 8;
        *(us8*)&dstBase[o] = *(const us8*)&src[o];
    }
    __syncthreads();

    const unsigned short* q = &qkvs[wave][0];
    const unsigned short* kk = &qkvs[wave][1024];
    const unsigned short* vv = &qkvs[wave][2048];
    const int h = lane >> 2, g4 = lane & 3;

    float s[4] = {0.f, 0.f, 0.f, 0.f};
    #pragma unroll
    for (int d0 = 0; d0 < 64; d0 += 8) {
        const us8 q8 = *(const us8*)&q[h * 64 + d0];
        float qf[8];
        #pragma unroll
        for (int e = 0; e < 8; ++e) qf[e] = bf2f(q8[e]);
        #pragma unroll
        for (int j = 0; j < 4; ++j) {
            const us8 k8 = *(const us8*)&kk[(g4 * 4 + j) * 64 + d0];
            #pragma unroll
            for (int e = 0; e < 8; ++e) s[j] += qf[e] * bf2f(k8[e]);
        }
    }
    #pragma unroll
    for (int j = 0; j < 4; ++j) s[j] *= 0.125f;

    float mx = fmaxf(fmaxf(s[0], s[1]), fmaxf(s[2], s[3]));
    mx = fmaxf(mx, __shfl_xor(mx, 1, 64));
    mx = fmaxf(mx, __shfl_xor(mx, 2, 64));
    float p[4], sum = 0.f;
    #pragma unroll
    for (int j = 0; j < 4; ++j) { p[j] = expf(s[j] - mx); sum += p[j]; }
    sum += __shfl_xor(sum, 1, 64);
    sum += __shfl_xor(sum, 2, 64);
    const float inv = 1.f / sum;
    #pragma unroll
    for (int j = 0; j < 4; ++j) ps[wave][h * 16 + g4 * 4 + j] = p[j] * inv;
    __syncthreads();

    const int db = lane & 3;
    float o16[16] = {};
    #pragma unroll
    for (int gq = 0; gq < 4; ++gq) {
        const f32x4 pv = *(const f32x4*)&ps[wave][h * 16 + gq * 4];
        #pragma unroll
        for (int j = 0; j < 4; ++j) {
            const float pg = pv[j];
            const int g = gq * 4 + j;
            const us8 v8a = *(const us8*)&vv[g * 64 + db * 16];
            const us8 v8b = *(const us8*)&vv[g * 64 + db * 16 + 8];
            #pragma unroll
            for (int e = 0; e < 8; ++e) {
                o16[e]     += pg * bf2f(v8a[e]);
                o16[8 + e] += pg * bf2f(v8b[e]);
            }
        }
    }
    us8 w0, w1;
    #pragma unroll
    for (int e = 0; e < 8; ++e) { w0[e] = f2bf(o16[e]); w1[e] = f2bf(o16[8 + e]); }
    *(us8*)&os[wave][h * 64 + db * 16] = w0;
    *(us8*)&os[wave][h * 64 + db * 16 + 8] = w1;
    __syncthreads();

    #pragma unroll
    for (int i = 0; i < 2; ++i) {
        const int c = i * 256 + tid;
        const int w2 = c >> 7;
        const int cc = c & 127;
        const long m = blockTok + w2;
        const long n_ = m >> 12;
        const int t = (int)(m & 4095);
        const int hh = cc >> 3, slot = cc & 7;
        const long row = n_ * 4096 + hh * 256 + (t >> 4);
        const long colb = (long)(t & 15) * 128 + slot * 16;
        *(us8*)((char*)out + row * 2048 + colb) = *(const us8*)&os[w2][cc * 8];
    }
}

// ---------------------------------------------------------------------------
extern "C" void kernel_launch(void* const* d_in, const int* in_sizes, int n_in,
                              void* d_out, int out_size, void* d_ws, size_t ws_size,
                              hipStream_t stream) {
    const float* x      = (const float*)d_in[0];  // (16,4096,1024)
    const float* w_qkv  = (const float*)d_in[1];  // (1024,3072)
    const float* b_qkv  = (const float*)d_in[2];  // (3072)
    const float* w_proj = (const float*)d_in[3];  // (1024,1024)
    const float* b_proj = (const float*)d_in[4];  // (1024)

    const long M = 65536;  // 16*4096 tokens
    const size_t QKV_B = (size_t)M * 3072 * 2;    // 402,653,184
    const size_t XB_B  = (size_t)M * 1024 * 2;    // 134,217,728 (x-bf16, then attnout)
    const size_t WQ_B  = 3072 * 1024 * 2;
    const size_t WP_B  = 1024 * 1024 * 2;
    if (ws_size < QKV_B + XB_B + WQ_B + WP_B) return;  // ~545MB

    char* ws = (char*)d_ws;
    unsigned short* qkv    = (unsigned short*)ws;
    unsigned short* xb     = (unsigned short*)(ws + QKV_B);          // also attnout
    unsigned short* wqkvT  = (unsigned short*)(ws + QKV_B + XB_B);
    unsigned short* wprojT = (unsigned short*)(ws + QKV_B + XB_B + WQ_B);

    hipFuncSetAttribute((const void*)gemm256<true>,
                        hipFuncAttributeMaxDynamicSharedMemorySize, 131072);
    hipFuncSetAttribute((const void*)gemm256<false>,
                        hipFuncAttributeMaxDynamicSharedMemorySize, 131072);

    dim3 tb(32, 8);
    transpose_cast<<<dim3(3072 / 32, 1024 / 32), tb, 0, stream>>>(w_qkv, wqkvT, 1024, 3072);
    transpose_cast<<<dim3(1024 / 32, 1024 / 32), tb, 0, stream>>>(w_proj, wprojT, 1024, 1024);
    cast_f32_bf16<<<2048, 256, 0, stream>>>(x, xb, M * 1024);

    // qkv = x @ w_qkv + b_qkv   (bf16 out); grid 12*256=3072 (%8==0)
    gemm256<true><<<dim3((3072 / 256) * (M / 256)), 512, 131072, stream>>>(
        xb, wqkvT, b_qkv, qkv, (int)M, 3072, 1024);

    // per-token attention -> scrambled attnout (bf16), reusing xb
    attn_kernel<<<dim3(M / 4), 256, 0, stream>>>(qkv, xb);

    // out = attnout @ w_proj + b_proj   (f32 out); grid 4*256=1024 (%8==0)
    gemm256<false><<<dim3((1024 / 256) * (M / 256)), 512, 131072, stream>>>(
        xb, wprojT, b_proj, d_out, (int)M, 1024, 1024);
}

// Round 10
// 784.953 us; speedup vs baseline: 1.0321x; 1.0321x over previous
//
#include <hip/hip_runtime.h>
#include <hip/hip_bf16.h>
#include <stdint.h>

typedef __bf16 bf16x8 __attribute__((ext_vector_type(8)));
typedef float f32x4 __attribute__((ext_vector_type(4)));
typedef unsigned short us8 __attribute__((ext_vector_type(8)));

__device__ __forceinline__ float bf2f(unsigned short u) {
    return __uint_as_float(((unsigned)u) << 16);
}
__device__ __forceinline__ unsigned short f2bf(float f) {
    __bf16 b = (__bf16)f;  // RNE
    return __builtin_bit_cast(unsigned short, b);
}

__device__ __forceinline__ void gload16(const char* g, char* l) {
    __builtin_amdgcn_global_load_lds(
        (const __attribute__((address_space(1))) void*)g,
        (__attribute__((address_space(3))) void*)l, 16, 0, 0);
}

// ---------------------------------------------------------------------------
// Transpose + cast: in (K x N) f32  ->  out (N x K) bf16
// ---------------------------------------------------------------------------
__global__ __launch_bounds__(256) void transpose_cast(
    const float* __restrict__ in, unsigned short* __restrict__ out,
    int K, int N)
{
    __shared__ float tile[32][33];
    const int tx = threadIdx.x, ty = threadIdx.y;  // (32, 8)
    const int n0 = blockIdx.x * 32, k0 = blockIdx.y * 32;
    #pragma unroll
    for (int i = 0; i < 32; i += 8)
        tile[ty + i][tx] = in[(long)(k0 + ty + i) * N + n0 + tx];
    __syncthreads();
    #pragma unroll
    for (int i = 0; i < 32; i += 8)
        out[(long)(n0 + ty + i) * K + k0 + tx] = f2bf(tile[tx][ty + i]);
}

// ---------------------------------------------------------------------------
// Elementwise cast f32 -> bf16 (vectorized, grid-stride)
// ---------------------------------------------------------------------------
__global__ __launch_bounds__(256) void cast_f32_bf16(
    const float* __restrict__ in, unsigned short* __restrict__ out, long n)
{
    const long stride = (long)gridDim.x * 256 * 8;
    for (long i = ((long)blockIdx.x * 256 + threadIdx.x) * 8; i < n; i += stride) {
        const f32x4 u0 = *(const f32x4*)&in[i];
        const f32x4 u1 = *(const f32x4*)&in[i + 4];
        us8 w;
        #pragma unroll
        for (int e = 0; e < 4; ++e) { w[e] = f2bf(u0[e]); w[e + 4] = f2bf(u1[e]); }
        *(us8*)&out[i] = w;
    }
}

// ---------------------------------------------------------------------------
// GEMM: C(M,N) = A(M,K) @ BT(N,K)^T + bias(N)       (A, BT bf16; K == 1024)
// 256x256 tile, BK=64, 512 threads (8 waves, 2M x 4N), 128KB dbuf LDS.
// r8 structure (best verified: 1047 TF, 0 bank conflicts): 8-phase
// counted-lgkm read-ahead, barriers only at staging phases (S3,S5,S6,S7),
// counted vmcnt(4) at S5; 16x16x32 MFMA whose read pattern is conflict-free
// under the (row&7)<<4 swizzle (r9's 32x32 pattern was NOT: 4-way aliasing).
// ---------------------------------------------------------------------------
#define MFMA16x16(a, b, c) __builtin_amdgcn_mfma_f32_16x16x32_bf16(a, b, c, 0, 0, 0)
#define BAR __builtin_amdgcn_s_barrier()
#define SB  __builtin_amdgcn_sched_barrier(0)
#define P1_ __builtin_amdgcn_s_setprio(1);
#define P0_ __builtin_amdgcn_s_setprio(0);

#define MFMA_H(AA, BB, RO, CO)                                                 \
    _Pragma("unroll") for (int mi_ = 0; mi_ < 4; ++mi_)                        \
        _Pragma("unroll") for (int ni_ = 0; ni_ < 2; ++ni_)                    \
            acc[(RO)+mi_][(CO)+ni_] =                                          \
                MFMA16x16(AA[mi_], BB[ni_], acc[(RO)+mi_][(CO)+ni_]);

#define RD_A(DST, BUFOFF, HIOFF, KS)                                           \
    _Pragma("unroll") for (int mi_ = 0; mi_ < 4; ++mi_)                        \
        DST[mi_] = *(const bf16x8*)(smem + (BUFOFF) + aBase + (HIOFF) + mi_*2048 + (KS));

#define RD_B(DST, BUFOFF, NOFF, KS)                                            \
    _Pragma("unroll") for (int ni_ = 0; ni_ < 2; ++ni_)                        \
        DST[ni_] = *(const bf16x8*)(smem + (BUFOFF) + bBase + ((NOFF)+ni_)*2048 + (KS));

// One K-tile = 8 phases S0..S7.  SG/SR are LITERAL 0/1 (folded).
#define TILE8(T_, BUF, OBUF, SG, SR)                                           \
  do {                                                                         \
    const long gk = (long)((T_) + 2) * 128;                                    \
    /* S0: rd AH0; mfma AL0xBL0 */                                             \
    RD_A(AH0, BUF, 8192, k0)                                                   \
    SB; asm volatile("s_waitcnt lgkmcnt(4)"); SB;                              \
    P1_ MFMA_H(AL0, BL0, 0, 0) P0_                                             \
    /* S1: rd BH0; mfma AH0xBL0 */                                             \
    RD_B(BH0, BUF, 2, k0)                                                      \
    SB; asm volatile("s_waitcnt lgkmcnt(2)"); SB;                              \
    P1_ MFMA_H(AH0, BL0, 4, 0) P0_                                             \
    /* S2: rd AL1; mfma AH0xBH0 */                                             \
    RD_A(AL1, BUF, 0, k1)                                                      \
    SB; asm volatile("s_waitcnt lgkmcnt(4)"); SB;                              \
    P1_ MFMA_H(AH0, BH0, 4, 2) P0_                                             \
    /* S3: rd BL1; stage A j0,j2; mfma AL0xBH0 */                              \
    BAR; RD_B(BL1, BUF, 0, k1)                                                 \
    if (SG) {                                                                  \
        gload16(aStage + (long)(0*64)*Kb + gk, smem + (BUF) + 0*8192 + ldsW);  \
        gload16(aStage + (long)(2*64)*Kb + gk, smem + (BUF) + 2*8192 + ldsW);  \
    }                                                                          \
    SB; asm volatile("s_waitcnt lgkmcnt(2)"); SB;                              \
    P1_ MFMA_H(AL0, BH0, 0, 2) P0_                                             \
    /* S4: rd AH1; mfma AL1xBL1 */                                             \
    RD_A(AH1, BUF, 8192, k1)                                                   \
    SB; asm volatile("s_waitcnt lgkmcnt(4)"); SB;                              \
    P1_ MFMA_H(AL1, BL1, 0, 0) P0_                                             \
    /* S5: rd BH1; stage A j1,j3; mfma AH1xBL1; counted vmcnt */               \
    BAR; RD_B(BH1, BUF, 2, k1)                                                 \
    if (SG) {                                                                  \
        gload16(aStage + (long)(1*64)*Kb + gk, smem + (BUF) + 1*8192 + ldsW);  \
        gload16(aStage + (long)(3*64)*Kb + gk, smem + (BUF) + 3*8192 + ldsW);  \
    }                                                                          \
    SB; asm volatile("s_waitcnt lgkmcnt(2)"); SB;                              \
    P1_ MFMA_H(AH1, BL1, 4, 0) P0_                                             \
    SB;                                                                        \
    if (SG) asm volatile("s_waitcnt vmcnt(4)");                                \
    else    asm volatile("s_waitcnt vmcnt(0)");                                \
    SB;                                                                        \
    /* S6: rd BL0'(OBUF); stage B j0,j1; mfma AH1xBH1 */                       \
    BAR;                                                                       \
    if (SR) { RD_B(BL0, OBUF, 0, k0) }                                         \
    if (SG) {                                                                  \
        gload16(bStage + (long)(0*64)*Kb + gk, smem + (BUF) + 32768 + 0*8192 + ldsW); \
        gload16(bStage + (long)(1*64)*Kb + gk, smem + (BUF) + 32768 + 1*8192 + ldsW); \
    }                                                                          \
    SB;                                                                        \
    if (SR) asm volatile("s_waitcnt lgkmcnt(2)");                              \
    else    asm volatile("s_waitcnt lgkmcnt(0)");                              \
    SB;                                                                        \
    P1_ MFMA_H(AH1, BH1, 4, 2) P0_                                             \
    /* S7: rd AL0'(OBUF); stage B j2,j3; mfma AL1xBH1 */                       \
    BAR;                                                                       \
    if (SR) { RD_A(AL0, OBUF, 0, k0) }                                         \
    if (SG) {                                                                  \
        gload16(bStage + (long)(2*64)*Kb + gk, smem + (BUF) + 32768 + 2*8192 + ldsW); \
        gload16(bStage + (long)(3*64)*Kb + gk, smem + (BUF) + 32768 + 3*8192 + ldsW); \
    }                                                                          \
    SB;                                                                        \
    if (SR) asm volatile("s_waitcnt lgkmcnt(4)");                              \
    else    asm volatile("s_waitcnt lgkmcnt(0)");                              \
    SB;                                                                        \
    P1_ MFMA_H(AL1, BH1, 0, 2) P0_                                             \
  } while (0)

template<bool OUT_BF16>
__global__ __launch_bounds__(512, 2)
void gemm256(const unsigned short* __restrict__ A,   // M x K bf16
             const unsigned short* __restrict__ BT,  // N x K bf16
             const float* __restrict__ bias,
             void* __restrict__ Cp,
             int M, int N, int K)
{
    extern __shared__ char smem[];   // 131072: 2 bufs x (A 32K | B 32K)
    const int tid  = threadIdx.x;
    const int lane = tid & 63;
    const int w    = tid >> 6;      // wave 0..7
    const int wm   = w >> 2;        // 0..1 (M split)
    const int wn   = w & 3;         // 0..3 (N split)

    // XCD-bijective swizzle (launcher guarantees gridDim.x % 8 == 0)
    const int nwg  = gridDim.x;
    const int bid0 = blockIdx.x;
    const int bid  = (bid0 & 7) * (nwg >> 3) + (bid0 >> 3);
    const int nbx  = N >> 8;
    const int bx   = bid % nbx, by = bid / nbx;
    const long rowStart = (long)by * 256;
    const int  colStart = bx * 256;

    const long Kb = (long)K * 2;     // row stride bytes (K == 1024, KT == 16)

    // staging: instr (mat, j) covers tile rows j*64 + w*8 + (lane>>3)
    const int srow = w * 8 + (lane >> 3);
    const int scol = ((lane & 7) ^ (lane >> 3)) << 4;   // inverse-swizzled src col
    const char* aStage = (const char*)A  + (rowStart + srow) * Kb + scol;
    const char* bStage = (const char*)BT + ((long)colStart + srow) * Kb + scol;
    const int ldsW = w * 1024;

    // fragment-read offsets (swizzled)
    const int fr = lane & 15;
    const int kq = lane >> 4;                      // 0..3
    const int sw = (fr & 7) << 4;
    const int k0 = (kq * 16) ^ sw;
    const int k1 = (64 + kq * 16) ^ sw;
    const int aBase = (wm * 128 + fr) * 128;           // bytes, A region
    const int bBase = 32768 + (wn * 64 + fr) * 128;    // bytes, B region

    f32x4 acc[8][4] = {};
    bf16x8 AL0[4], AH0[4], AL1[4], AH1[4], BL0[2], BH0[2], BL1[2], BH1[2];

    // ---- prologue: stage K-tiles 0 (buf0) and 1 (buf1) ----
    #pragma unroll
    for (int tt = 0; tt < 2; ++tt) {
        #pragma unroll
        for (int j = 0; j < 4; ++j)
            gload16(aStage + (long)(j * 64) * Kb + (long)tt * 128,
                    smem + tt * 65536 + j * 8192 + ldsW);
        #pragma unroll
        for (int j = 0; j < 4; ++j)
            gload16(bStage + (long)(j * 64) * Kb + (long)tt * 128,
                    smem + tt * 65536 + 32768 + j * 8192 + ldsW);
    }
    asm volatile("s_waitcnt vmcnt(8)");   // tile 0 landed; tile 1 in flight
    BAR;                                   // publish tile-0 stages
    RD_B(BL0, 0, 0, k0)                    // preload S0 operands (6 reads)
    RD_A(AL0, 0, 0, k0)
    // S0's lgkmcnt(4) (after its 4 AH0 reads) drains these 6.

    #pragma unroll 1
    for (int tp = 0; tp < 7; ++tp) {       // tiles 0..13, full pipeline
        TILE8(2 * tp,     0,     65536, 1, 1);
        TILE8(2 * tp + 1, 65536, 0,     1, 1);
    }
    TILE8(14, 0,     65536, 0, 1);         // no staging; drain vmcnt
    TILE8(15, 65536, 0,     0, 0);         // tail: no next-tile reads

    // ---- epilogue: C/D frag layout col=lane&15, row=(lane>>4)*4+e ----
    float bv[4];
    #pragma unroll
    for (int ni = 0; ni < 4; ++ni)
        bv[ni] = bias[colStart + wn * 64 + ni * 16 + fr];
    #pragma unroll
    for (int mi = 0; mi < 8; ++mi) {
        #pragma unroll
        for (int ni = 0; ni < 4; ++ni) {
            const int col = colStart + wn * 64 + ni * 16 + fr;
            #pragma unroll
            for (int e = 0; e < 4; ++e) {
                const long row = rowStart + wm * 128 + mi * 16 + kq * 4 + e;
                const float val = acc[mi][ni][e] + bv[ni];
                if constexpr (OUT_BF16)
                    ((unsigned short*)Cp)[row * N + col] = f2bf(val);
                else
                    ((float*)Cp)[row * N + col] = val;
            }
        }
    }
}

// ---------------------------------------------------------------------------
// Per-token head-mixing attention.  One wave per token; output stored
// DIRECTLY from the computing lane (addressing verified identical to the
// previous LDS-staged scatter; drops one __syncthreads + 8KB LDS round-trip).
// ---------------------------------------------------------------------------
__global__ __launch_bounds__(256) void attn_kernel(
    const unsigned short* __restrict__ qkv, unsigned short* __restrict__ out)
{
    __shared__ unsigned short qkvs[4][3072];
    __shared__ float ps[4][256];
    const int tid = threadIdx.x, lane = tid & 63, wave = tid >> 6;
    const long blockTok = (long)blockIdx.x * 4;

    const unsigned short* src = qkv + blockTok * 3072;
    unsigned short* dstBase = &qkvs[0][0];
    #pragma unroll
    for (int i = 0; i < 6; ++i) {
        const int o = (i * 256 + tid) * 8;
        *(us8*)&dstBase[o] = *(const us8*)&src[o];
    }
    __syncthreads();

    const unsigned short* q = &qkvs[wave][0];
    const unsigned short* kk = &qkvs[wave][1024];
    const unsigned short* vv = &qkvs[wave][2048];
    const int h = lane >> 2, g4 = lane & 3;

    float s[4] = {0.f, 0.f, 0.f, 0.f};
    #pragma unroll
    for (int d0 = 0; d0 < 64; d0 += 8) {
        const us8 q8 = *(const us8*)&q[h * 64 + d0];
        float qf[8];
        #pragma unroll
        for (int e = 0; e < 8; ++e) qf[e] = bf2f(q8[e]);
        #pragma unroll
        for (int j = 0; j < 4; ++j) {
            const us8 k8 = *(const us8*)&kk[(g4 * 4 + j) * 64 + d0];
            #pragma unroll
            for (int e = 0; e < 8; ++e) s[j] += qf[e] * bf2f(k8[e]);
        }
    }
    #pragma unroll
    for (int j = 0; j < 4; ++j) s[j] *= 0.125f;

    float mx = fmaxf(fmaxf(s[0], s[1]), fmaxf(s[2], s[3]));
    mx = fmaxf(mx, __shfl_xor(mx, 1, 64));
    mx = fmaxf(mx, __shfl_xor(mx, 2, 64));
    float p[4], sum = 0.f;
    #pragma unroll
    for (int j = 0; j < 4; ++j) { p[j] = expf(s[j] - mx); sum += p[j]; }
    sum += __shfl_xor(sum, 1, 64);
    sum += __shfl_xor(sum, 2, 64);
    const float inv = 1.f / sum;
    #pragma unroll
    for (int j = 0; j < 4; ++j) ps[wave][h * 16 + g4 * 4 + j] = p[j] * inv;
    __syncthreads();

    // PV: lane handles d in [db*16, db*16+16) for head h; store direct.
    const int db = lane & 3;
    float o16[16] = {};
    #pragma unroll
    for (int gq = 0; gq < 4; ++gq) {
        const f32x4 pv = *(const f32x4*)&ps[wave][h * 16 + gq * 4];
        #pragma unroll
        for (int j = 0; j < 4; ++j) {
            const float pg = pv[j];
            const int g = gq * 4 + j;
            const us8 v8a = *(const us8*)&vv[g * 64 + db * 16];
            const us8 v8b = *(const us8*)&vv[g * 64 + db * 16 + 8];
            #pragma unroll
            for (int e = 0; e < 8; ++e) {
                o16[e]     += pg * bf2f(v8a[e]);
                o16[8 + e] += pg * bf2f(v8b[e]);
            }
        }
    }
    us8 w0, w1;
    #pragma unroll
    for (int e = 0; e < 8; ++e) { w0[e] = f2bf(o16[e]); w1[e] = f2bf(o16[8 + e]); }

    // scrambled layout: row = n*4096 + h*256 + (t>>4); col = (t&15)*64 + d
    const long m = blockTok + wave;
    const long n_ = m >> 12;               // T = 4096
    const int t  = (int)(m & 4095);
    const long base = (n_ * 4096 + h * 256 + (t >> 4)) * 1024
                    + (t & 15) * 64 + db * 16;
    *(us8*)&out[base]     = w0;
    *(us8*)&out[base + 8] = w1;
}

// ---------------------------------------------------------------------------
extern "C" void kernel_launch(void* const* d_in, const int* in_sizes, int n_in,
                              void* d_out, int out_size, void* d_ws, size_t ws_size,
                              hipStream_t stream) {
    const float* x      = (const float*)d_in[0];  // (16,4096,1024)
    const float* w_qkv  = (const float*)d_in[1];  // (1024,3072)
    const float* b_qkv  = (const float*)d_in[2];  // (3072)
    const float* w_proj = (const float*)d_in[3];  // (1024,1024)
    const float* b_proj = (const float*)d_in[4];  // (1024)

    const long M = 65536;  // 16*4096 tokens
    const size_t QKV_B = (size_t)M * 3072 * 2;    // 402,653,184
    const size_t XB_B  = (size_t)M * 1024 * 2;    // 134,217,728 (x-bf16, then attnout)
    const size_t WQ_B  = 3072 * 1024 * 2;
    const size_t WP_B  = 1024 * 1024 * 2;
    if (ws_size < QKV_B + XB_B + WQ_B + WP_B) return;  // ~545MB

    char* ws = (char*)d_ws;
    unsigned short* qkv    = (unsigned short*)ws;
    unsigned short* xb     = (unsigned short*)(ws + QKV_B);          // also attnout
    unsigned short* wqkvT  = (unsigned short*)(ws + QKV_B + XB_B);
    unsigned short* wprojT = (unsigned short*)(ws + QKV_B + XB_B + WQ_B);

    hipFuncSetAttribute((const void*)gemm256<true>,
                        hipFuncAttributeMaxDynamicSharedMemorySize, 131072);
    hipFuncSetAttribute((const void*)gemm256<false>,
                        hipFuncAttributeMaxDynamicSharedMemorySize, 131072);

    dim3 tb(32, 8);
    transpose_cast<<<dim3(3072 / 32, 1024 / 32), tb, 0, stream>>>(w_qkv, wqkvT, 1024, 3072);
    transpose_cast<<<dim3(1024 / 32, 1024 / 32), tb, 0, stream>>>(w_proj, wprojT, 1024, 1024);
    cast_f32_bf16<<<2048, 256, 0, stream>>>(x, xb, M * 1024);

    // qkv = x @ w_qkv + b_qkv   (bf16 out); grid 12*256=3072 (%8==0)
    gemm256<true><<<dim3((3072 / 256) * (M / 256)), 512, 131072, stream>>>(
        xb, wqkvT, b_qkv, qkv, (int)M, 3072, 1024);

    // per-token attention -> scrambled attnout (bf16), reusing xb
    attn_kernel<<<dim3(M / 4), 256, 0, stream>>>(qkv, xb);

    // out = attnout @ w_proj + b_proj   (f32 out); grid 4*256=1024 (%8==0)
    gemm256<false><<<dim3((1024 / 256) * (M / 256)), 512, 131072, stream>>>(
        xb, wprojT, b_proj, d_out, (int)M, 1024, 1024);
}

// Round 11
// 718.489 us; speedup vs baseline: 1.1275x; 1.0925x over previous
//
#include <hip/hip_runtime.h>
#include <hip/hip_bf16.h>
#include <stdint.h>

typedef __bf16 bf16x8 __attribute__((ext_vector_type(8)));
typedef float f32x4 __attribute__((ext_vector_type(4)));
typedef unsigned short us8 __attribute__((ext_vector_type(8)));

__device__ __forceinline__ float bf2f(unsigned short u) {
    return __uint_as_float(((unsigned)u) << 16);
}
__device__ __forceinline__ unsigned short f2bf(float f) {
    __bf16 b = (__bf16)f;  // RNE
    return __builtin_bit_cast(unsigned short, b);
}

__device__ __forceinline__ void gload16(const char* g, char* l) {
    __builtin_amdgcn_global_load_lds(
        (const __attribute__((address_space(1))) void*)g,
        (__attribute__((address_space(3))) void*)l, 16, 0, 0);
}

// ---------------------------------------------------------------------------
// Transpose + cast: in (K x N) f32  ->  out (N x K) bf16
// ---------------------------------------------------------------------------
__global__ __launch_bounds__(256) void transpose_cast(
    const float* __restrict__ in, unsigned short* __restrict__ out,
    int K, int N)
{
    __shared__ float tile[32][33];
    const int tx = threadIdx.x, ty = threadIdx.y;  // (32, 8)
    const int n0 = blockIdx.x * 32, k0 = blockIdx.y * 32;
    #pragma unroll
    for (int i = 0; i < 32; i += 8)
        tile[ty + i][tx] = in[(long)(k0 + ty + i) * N + n0 + tx];
    __syncthreads();
    #pragma unroll
    for (int i = 0; i < 32; i += 8)
        out[(long)(n0 + ty + i) * K + k0 + tx] = f2bf(tile[tx][ty + i]);
}

// ---------------------------------------------------------------------------
// Elementwise cast f32 -> bf16 (vectorized, grid-stride)
// ---------------------------------------------------------------------------
__global__ __launch_bounds__(256) void cast_f32_bf16(
    const float* __restrict__ in, unsigned short* __restrict__ out, long n)
{
    const long stride = (long)gridDim.x * 256 * 8;
    for (long i = ((long)blockIdx.x * 256 + threadIdx.x) * 8; i < n; i += stride) {
        const f32x4 u0 = *(const f32x4*)&in[i];
        const f32x4 u1 = *(const f32x4*)&in[i + 4];
        us8 w;
        #pragma unroll
        for (int e = 0; e < 4; ++e) { w[e] = f2bf(u0[e]); w[e + 4] = f2bf(u1[e]); }
        *(us8*)&out[i] = w;
    }
}

// ---------------------------------------------------------------------------
// GEMM: C(M,N) = A(M,K) @ BT(N,K)^T + bias(N)       (A, BT bf16; K == 1024)
// 256x256 tile, BK=64, 512 threads (8 waves, 2M x 4N), 128KB dbuf LDS.
// r8 structure (best verified: 1047 TF, 0 bank conflicts): 8-phase
// counted-lgkm read-ahead, barriers only at staging phases (S3,S5,S6,S7),
// counted vmcnt(4) at S5; 16x16x32 MFMA whose read pattern is conflict-free
// under the (row&7)<<4 swizzle (r9's 32x32 pattern was NOT: 4-way aliasing).
// ---------------------------------------------------------------------------
#define MFMA16x16(a, b, c) __builtin_amdgcn_mfma_f32_16x16x32_bf16(a, b, c, 0, 0, 0)
#define BAR __builtin_amdgcn_s_barrier()
#define SB  __builtin_amdgcn_sched_barrier(0)
#define P1_ __builtin_amdgcn_s_setprio(1);
#define P0_ __builtin_amdgcn_s_setprio(0);

#define MFMA_H(AA, BB, RO, CO)                                                 \
    _Pragma("unroll") for (int mi_ = 0; mi_ < 4; ++mi_)                        \
        _Pragma("unroll") for (int ni_ = 0; ni_ < 2; ++ni_)                    \
            acc[(RO)+mi_][(CO)+ni_] =                                          \
                MFMA16x16(AA[mi_], BB[ni_], acc[(RO)+mi_][(CO)+ni_]);

#define RD_A(DST, BUFOFF, HIOFF, KS)                                           \
    _Pragma("unroll") for (int mi_ = 0; mi_ < 4; ++mi_)                        \
        DST[mi_] = *(const bf16x8*)(smem + (BUFOFF) + aBase + (HIOFF) + mi_*2048 + (KS));

#define RD_B(DST, BUFOFF, NOFF, KS)                                            \
    _Pragma("unroll") for (int ni_ = 0; ni_ < 2; ++ni_)                        \
        DST[ni_] = *(const bf16x8*)(smem + (BUFOFF) + bBase + ((NOFF)+ni_)*2048 + (KS));

// One K-tile = 8 phases S0..S7.  SG/SR are LITERAL 0/1 (folded).
#define TILE8(T_, BUF, OBUF, SG, SR)                                           \
  do {                                                                         \
    const long gk = (long)((T_) + 2) * 128;                                    \
    /* S0: rd AH0; mfma AL0xBL0 */                                             \
    RD_A(AH0, BUF, 8192, k0)                                                   \
    SB; asm volatile("s_waitcnt lgkmcnt(4)"); SB;                              \
    P1_ MFMA_H(AL0, BL0, 0, 0) P0_                                             \
    /* S1: rd BH0; mfma AH0xBL0 */                                             \
    RD_B(BH0, BUF, 2, k0)                                                      \
    SB; asm volatile("s_waitcnt lgkmcnt(2)"); SB;                              \
    P1_ MFMA_H(AH0, BL0, 4, 0) P0_                                             \
    /* S2: rd AL1; mfma AH0xBH0 */                                             \
    RD_A(AL1, BUF, 0, k1)                                                      \
    SB; asm volatile("s_waitcnt lgkmcnt(4)"); SB;                              \
    P1_ MFMA_H(AH0, BH0, 4, 2) P0_                                             \
    /* S3: rd BL1; stage A j0,j2; mfma AL0xBH0 */                              \
    BAR; RD_B(BL1, BUF, 0, k1)                                                 \
    if (SG) {                                                                  \
        gload16(aStage + (long)(0*64)*Kb + gk, smem + (BUF) + 0*8192 + ldsW);  \
        gload16(aStage + (long)(2*64)*Kb + gk, smem + (BUF) + 2*8192 + ldsW);  \
    }                                                                          \
    SB; asm volatile("s_waitcnt lgkmcnt(2)"); SB;                              \
    P1_ MFMA_H(AL0, BH0, 0, 2) P0_                                             \
    /* S4: rd AH1; mfma AL1xBL1 */                                             \
    RD_A(AH1, BUF, 8192, k1)                                                   \
    SB; asm volatile("s_waitcnt lgkmcnt(4)"); SB;                              \
    P1_ MFMA_H(AL1, BL1, 0, 0) P0_                                             \
    /* S5: rd BH1; stage A j1,j3; mfma AH1xBL1; counted vmcnt */               \
    BAR; RD_B(BH1, BUF, 2, k1)                                                 \
    if (SG) {                                                                  \
        gload16(aStage + (long)(1*64)*Kb + gk, smem + (BUF) + 1*8192 + ldsW);  \
        gload16(aStage + (long)(3*64)*Kb + gk, smem + (BUF) + 3*8192 + ldsW);  \
    }                                                                          \
    SB; asm volatile("s_waitcnt lgkmcnt(2)"); SB;                              \
    P1_ MFMA_H(AH1, BL1, 4, 0) P0_                                             \
    SB;                                                                        \
    if (SG) asm volatile("s_waitcnt vmcnt(4)");                                \
    else    asm volatile("s_waitcnt vmcnt(0)");                                \
    SB;                                                                        \
    /* S6: rd BL0'(OBUF); stage B j0,j1; mfma AH1xBH1 */                       \
    BAR;                                                                       \
    if (SR) { RD_B(BL0, OBUF, 0, k0) }                                         \
    if (SG) {                                                                  \
        gload16(bStage + (long)(0*64)*Kb + gk, smem + (BUF) + 32768 + 0*8192 + ldsW); \
        gload16(bStage + (long)(1*64)*Kb + gk, smem + (BUF) + 32768 + 1*8192 + ldsW); \
    }                                                                          \
    SB;                                                                        \
    if (SR) asm volatile("s_waitcnt lgkmcnt(2)");                              \
    else    asm volatile("s_waitcnt lgkmcnt(0)");                              \
    SB;                                                                        \
    P1_ MFMA_H(AH1, BH1, 4, 2) P0_                                             \
    /* S7: rd AL0'(OBUF); stage B j2,j3; mfma AL1xBH1 */                       \
    BAR;                                                                       \
    if (SR) { RD_A(AL0, OBUF, 0, k0) }                                         \
    if (SG) {                                                                  \
        gload16(bStage + (long)(2*64)*Kb + gk, smem + (BUF) + 32768 + 2*8192 + ldsW); \
        gload16(bStage + (long)(3*64)*Kb + gk, smem + (BUF) + 32768 + 3*8192 + ldsW); \
    }                                                                          \
    SB;                                                                        \
    if (SR) asm volatile("s_waitcnt lgkmcnt(4)");                              \
    else    asm volatile("s_waitcnt lgkmcnt(0)");                              \
    SB;                                                                        \
    P1_ MFMA_H(AL1, BH1, 0, 2) P0_                                             \
  } while (0)

template<bool OUT_BF16>
__global__ __launch_bounds__(512, 2)
void gemm256(const unsigned short* __restrict__ A,   // M x K bf16
             const unsigned short* __restrict__ BT,  // N x K bf16
             const float* __restrict__ bias,
             void* __restrict__ Cp,
             int M, int N, int K)
{
    extern __shared__ char smem[];   // 131072: 2 bufs x (A 32K | B 32K)
    const int tid  = threadIdx.x;
    const int lane = tid & 63;
    const int w    = tid >> 6;      // wave 0..7
    const int wm   = w >> 2;        // 0..1 (M split)
    const int wn   = w & 3;         // 0..3 (N split)

    // XCD-bijective swizzle (launcher guarantees gridDim.x % 8 == 0)
    const int nwg  = gridDim.x;
    const int bid0 = blockIdx.x;
    const int bid  = (bid0 & 7) * (nwg >> 3) + (bid0 >> 3);
    const int nbx  = N >> 8;
    const int bx   = bid % nbx, by = bid / nbx;
    const long rowStart = (long)by * 256;
    const int  colStart = bx * 256;

    const long Kb = (long)K * 2;     // row stride bytes (K == 1024, KT == 16)

    // staging: instr (mat, j) covers tile rows j*64 + w*8 + (lane>>3)
    const int srow = w * 8 + (lane >> 3);
    const int scol = ((lane & 7) ^ (lane >> 3)) << 4;   // inverse-swizzled src col
    const char* aStage = (const char*)A  + (rowStart + srow) * Kb + scol;
    const char* bStage = (const char*)BT + ((long)colStart + srow) * Kb + scol;
    const int ldsW = w * 1024;

    // fragment-read offsets (swizzled)
    const int fr = lane & 15;
    const int kq = lane >> 4;                      // 0..3
    const int sw = (fr & 7) << 4;
    const int k0 = (kq * 16) ^ sw;
    const int k1 = (64 + kq * 16) ^ sw;
    const int aBase = (wm * 128 + fr) * 128;           // bytes, A region
    const int bBase = 32768 + (wn * 64 + fr) * 128;    // bytes, B region

    f32x4 acc[8][4] = {};
    bf16x8 AL0[4], AH0[4], AL1[4], AH1[4], BL0[2], BH0[2], BL1[2], BH1[2];

    // ---- prologue: stage K-tiles 0 (buf0) and 1 (buf1) ----
    #pragma unroll
    for (int tt = 0; tt < 2; ++tt) {
        #pragma unroll
        for (int j = 0; j < 4; ++j)
            gload16(aStage + (long)(j * 64) * Kb + (long)tt * 128,
                    smem + tt * 65536 + j * 8192 + ldsW);
        #pragma unroll
        for (int j = 0; j < 4; ++j)
            gload16(bStage + (long)(j * 64) * Kb + (long)tt * 128,
                    smem + tt * 65536 + 32768 + j * 8192 + ldsW);
    }
    asm volatile("s_waitcnt vmcnt(8)");   // tile 0 landed; tile 1 in flight
    BAR;                                   // publish tile-0 stages
    RD_B(BL0, 0, 0, k0)                    // preload S0 operands (6 reads)
    RD_A(AL0, 0, 0, k0)
    // S0's lgkmcnt(4) (after its 4 AH0 reads) drains these 6.

    #pragma unroll 1
    for (int tp = 0; tp < 7; ++tp) {       // tiles 0..13, full pipeline
        TILE8(2 * tp,     0,     65536, 1, 1);
        TILE8(2 * tp + 1, 65536, 0,     1, 1);
    }
    TILE8(14, 0,     65536, 0, 1);         // no staging; drain vmcnt
    TILE8(15, 65536, 0,     0, 0);         // tail: no next-tile reads

    // ---- epilogue: C/D frag layout col=lane&15, row=(lane>>4)*4+e ----
    float bv[4];
    #pragma unroll
    for (int ni = 0; ni < 4; ++ni)
        bv[ni] = bias[colStart + wn * 64 + ni * 16 + fr];
    #pragma unroll
    for (int mi = 0; mi < 8; ++mi) {
        #pragma unroll
        for (int ni = 0; ni < 4; ++ni) {
            const int col = colStart + wn * 64 + ni * 16 + fr;
            #pragma unroll
            for (int e = 0; e < 4; ++e) {
                const long row = rowStart + wm * 128 + mi * 16 + kq * 4 + e;
                const float val = acc[mi][ni][e] + bv[ni];
                if constexpr (OUT_BF16)
                    ((unsigned short*)Cp)[row * N + col] = f2bf(val);
                else
                    ((float*)Cp)[row * N + col] = val;
            }
        }
    }
}

// ---------------------------------------------------------------------------
// Per-token head-mixing attention.  One wave per token.
// QK^T now via MFMA 16x16x32 (fragment mappings identical to the GEMM's,
// all verified): A row = q[lane&15] @ k-offset (lane>>4)*8; B (B^T layout)
// row = kk[lane&15]; D: col=lane&15 -> g, row=(lane>>4)*4+r -> h.
// Softmax: 16-lane shfl_xor reduce over g.  P -> LDS f32 (stride 20, 2-way
// max bank alias = free).  PV + LDS-staged coalesced scatter = r8-verified.
// ---------------------------------------------------------------------------
__global__ __launch_bounds__(256) void attn_kernel(
    const unsigned short* __restrict__ qkv, unsigned short* __restrict__ out)
{
    __shared__ unsigned short qkvs[4][3072];
    __shared__ float ps[4][320];           // [h*20 + g], padded stride
    __shared__ unsigned short os[4][1024];
    const int tid = threadIdx.x, lane = tid & 63, wave = tid >> 6;
    const long blockTok = (long)blockIdx.x * 4;

    // stage 4 contiguous token rows (24KB)
    const unsigned short* src = qkv + blockTok * 3072;
    unsigned short* dstBase = &qkvs[0][0];
    #pragma unroll
    for (int i = 0; i < 6; ++i) {
        const int o = (i * 256 + tid) * 8;
        *(us8*)&dstBase[o] = *(const us8*)&src[o];
    }
    __syncthreads();

    const unsigned short* q  = &qkvs[wave][0];
    const unsigned short* kk = &qkvs[wave][1024];
    const unsigned short* vv = &qkvs[wave][2048];

    // ---- QK^T via 2x MFMA: s[h][g] = sum_d q[h][d] k[g][d] ----
    const int fr = lane & 15, kq = lane >> 4;
    const int fo = fr * 64 + kq * 8;
    const bf16x8 aq0 = *(const bf16x8*)&q[fo];
    const bf16x8 aq1 = *(const bf16x8*)&q[fo + 32];
    const bf16x8 bk0 = *(const bf16x8*)&kk[fo];
    const bf16x8 bk1 = *(const bf16x8*)&kk[fo + 32];
    f32x4 s = {};
    s = __builtin_amdgcn_mfma_f32_16x16x32_bf16(aq0, bk0, s, 0, 0, 0);
    s = __builtin_amdgcn_mfma_f32_16x16x32_bf16(aq1, bk1, s, 0, 0, 0);

    // ---- softmax over g (16-lane group reduce); lane holds h=kq*4+r, g=fr
    #pragma unroll
    for (int r = 0; r < 4; ++r) {
        const float v_ = s[r] * 0.125f;
        float m_ = v_;
        m_ = fmaxf(m_, __shfl_xor(m_, 1, 64));
        m_ = fmaxf(m_, __shfl_xor(m_, 2, 64));
        m_ = fmaxf(m_, __shfl_xor(m_, 4, 64));
        m_ = fmaxf(m_, __shfl_xor(m_, 8, 64));
        const float p_ = expf(v_ - m_);
        float t_ = p_;
        t_ += __shfl_xor(t_, 1, 64);
        t_ += __shfl_xor(t_, 2, 64);
        t_ += __shfl_xor(t_, 4, 64);
        t_ += __shfl_xor(t_, 8, 64);
        ps[wave][(kq * 4 + r) * 20 + fr] = p_ / t_;
    }
    __syncthreads();

    // ---- PV: lane handles d in [db*16, db*16+16) for head h ----
    const int h = lane >> 2, db = lane & 3;
    float o16[16] = {};
    #pragma unroll
    for (int gq = 0; gq < 4; ++gq) {
        const f32x4 pv = *(const f32x4*)&ps[wave][h * 20 + gq * 4];
        #pragma unroll
        for (int j = 0; j < 4; ++j) {
            const float pg = pv[j];
            const int g = gq * 4 + j;
            const us8 v8a = *(const us8*)&vv[g * 64 + db * 16];
            const us8 v8b = *(const us8*)&vv[g * 64 + db * 16 + 8];
            #pragma unroll
            for (int e = 0; e < 8; ++e) {
                o16[e]     += pg * bf2f(v8a[e]);
                o16[8 + e] += pg * bf2f(v8b[e]);
            }
        }
    }
    us8 w0, w1;
    #pragma unroll
    for (int e = 0; e < 8; ++e) { w0[e] = f2bf(o16[e]); w1[e] = f2bf(o16[8 + e]); }
    *(us8*)&os[wave][h * 64 + db * 16] = w0;
    *(us8*)&os[wave][h * 64 + db * 16 + 8] = w1;
    __syncthreads();

    // ---- scatter 4 tokens x 2KB to scrambled layout, 16B chunks ----
    #pragma unroll
    for (int i = 0; i < 2; ++i) {
        const int c = i * 256 + tid;
        const int w2 = c >> 7;
        const int cc = c & 127;
        const long m = blockTok + w2;
        const long n_ = m >> 12;
        const int t = (int)(m & 4095);
        const int hh = cc >> 3, slot = cc & 7;
        const long row = n_ * 4096 + hh * 256 + (t >> 4);
        const long colb = (long)(t & 15) * 128 + slot * 16;
        *(us8*)((char*)out + row * 2048 + colb) = *(const us8*)&os[w2][cc * 8];
    }
}

// ---------------------------------------------------------------------------
extern "C" void kernel_launch(void* const* d_in, const int* in_sizes, int n_in,
                              void* d_out, int out_size, void* d_ws, size_t ws_size,
                              hipStream_t stream) {
    const float* x      = (const float*)d_in[0];  // (16,4096,1024)
    const float* w_qkv  = (const float*)d_in[1];  // (1024,3072)
    const float* b_qkv  = (const float*)d_in[2];  // (3072)
    const float* w_proj = (const float*)d_in[3];  // (1024,1024)
    const float* b_proj = (const float*)d_in[4];  // (1024)

    const long M = 65536;  // 16*4096 tokens
    const size_t QKV_B = (size_t)M * 3072 * 2;    // 402,653,184
    const size_t XB_B  = (size_t)M * 1024 * 2;    // 134,217,728 (x-bf16, then attnout)
    const size_t WQ_B  = 3072 * 1024 * 2;
    const size_t WP_B  = 1024 * 1024 * 2;
    if (ws_size < QKV_B + XB_B + WQ_B + WP_B) return;  // ~545MB

    char* ws = (char*)d_ws;
    unsigned short* qkv    = (unsigned short*)ws;
    unsigned short* xb     = (unsigned short*)(ws + QKV_B);          // also attnout
    unsigned short* wqkvT  = (unsigned short*)(ws + QKV_B + XB_B);
    unsigned short* wprojT = (unsigned short*)(ws + QKV_B + XB_B + WQ_B);

    hipFuncSetAttribute((const void*)gemm256<true>,
                        hipFuncAttributeMaxDynamicSharedMemorySize, 131072);
    hipFuncSetAttribute((const void*)gemm256<false>,
                        hipFuncAttributeMaxDynamicSharedMemorySize, 131072);

    dim3 tb(32, 8);
    transpose_cast<<<dim3(3072 / 32, 1024 / 32), tb, 0, stream>>>(w_qkv, wqkvT, 1024, 3072);
    transpose_cast<<<dim3(1024 / 32, 1024 / 32), tb, 0, stream>>>(w_proj, wprojT, 1024, 1024);
    cast_f32_bf16<<<2048, 256, 0, stream>>>(x, xb, M * 1024);

    // qkv = x @ w_qkv + b_qkv   (bf16 out); grid 12*256=3072 (%8==0)
    gemm256<true><<<dim3((3072 / 256) * (M / 256)), 512, 131072, stream>>>(
        xb, wqkvT, b_qkv, qkv, (int)M, 3072, 1024);

    // per-token attention -> scrambled attnout (bf16), reusing xb
    attn_kernel<<<dim3(M / 4), 256, 0, stream>>>(qkv, xb);

    // out = attnout @ w_proj + b_proj   (f32 out); grid 4*256=1024 (%8==0)
    gemm256<false><<<dim3((1024 / 256) * (M / 256)), 512, 131072, stream>>>(
        xb, wprojT, b_proj, d_out, (int)M, 1024, 1024);
}